// Round 18
// baseline (65.394 us; speedup 1.0000x reference)
//
#include <hip/hip_runtime.h>

// Problem constants (fixed by setup_inputs)
#define B_    16
#define N_    262144            // 2^18 pixels per image
#define NC    150               // classes
#define NP    4096              // pred segment ids
#define T_    (B_ * NC)         // 2400 distinct target ids
#define TOTAL (B_ * N_)         // 4,194,304 pixels

#define NSUB   1024             // sub-buckets (pred>>2), 4 pred rows each
#define SEGS   1024             // partition blocks
#define SEGPIX 4096             // pixels (records) per segment
#define QT     9600             // local keys per sub-bucket block (4*2400)

typedef unsigned int u32;
typedef unsigned short u16;

// ---------------------------------------------------------------------------
// Kernel 1: staged radix-split by pred>>2 (1024 bins), single input pass,
// rank-fused, contiguous flush. meta[(seg,sub)] = (lstart<<16)|cnt.
// ---------------------------------------------------------------------------
__global__ __launch_bounds__(256) void partition_kernel(const int* __restrict__ pred,
                                                        const int* __restrict__ tgt,
                                                        u16* __restrict__ recSeg,
                                                        u32* __restrict__ metaArr,
                                                        u16* __restrict__ ntPart) {
    __shared__ u32 keybuf[SEGPIX];   // 16 KB: (sub<<16)|lk
    __shared__ u16 rankbuf[SEGPIX];  // 8 KB: within-(block,sub) rank
    __shared__ u16 staging[SEGPIX];  // 8 KB: sub-bucket-sorted u16 records
    __shared__ u32 cnt32[NSUB / 2];  // 2 KB: two u16 counters per word
    __shared__ u32 lstart[NSUB];     // 4 KB
    __shared__ u32 nth[NC];          // 600 B
    __shared__ u32 wsum[4];

    int tid = threadIdx.x;
    int blk = blockIdx.x;
    cnt32[tid] = 0;
    cnt32[tid + 256] = 0;
    if (tid < NC) nth[tid] = 0;
    __syncthreads();

    int base = blk * SEGPIX;
    int b_img = base >> 18;                  // constant per block
    const int4* pred4 = (const int4*)pred;
    const int4* tgt4  = (const int4*)tgt;

    // ---- phase A: read once; key + rank into LDS; packed counts ----
    #pragma unroll
    for (int k = 0; k < 4; ++k) {
        int vi = (base >> 2) + k * 256 + tid;
        int4 pv = pred4[vi];
        int4 tv = tgt4[vi];
        int pe[4] = {pv.x, pv.y, pv.z, pv.w};
        int te[4] = {tv.x, tv.y, tv.z, tv.w};
        #pragma unroll
        for (int e = 0; e < 4; ++e) {
            int p = pe[e];
            u32 sub = (u32)(p >> 2);
            u32 lk  = (u32)((p & 15) * T_ + b_img * NC + te[e]);
            int flat = (k * 256 + tid) * 4 + e;
            u32 shift = (sub & 1u) * 16u;
            u32 old = atomicAdd(&cnt32[sub >> 1], 1u << shift);
            keybuf[flat]  = (sub << 16) | lk;
            rankbuf[flat] = (u16)((old >> shift) & 0xFFFFu);
            atomicAdd(&nth[te[e]], 1u);
        }
    }
    __syncthreads();

    // ---- phase B: two-level exclusive scan over 1024 counts ----
    {
        u32 w0 = cnt32[2 * tid], w1 = cnt32[2 * tid + 1];
        u32 c0 = w0 & 0xFFFFu, c1 = w0 >> 16, c2 = w1 & 0xFFFFu, c3 = w1 >> 16;
        u32 tot = c0 + c1 + c2 + c3;
        u32 v = tot;
        #pragma unroll
        for (int o = 1; o < 64; o <<= 1) {
            u32 t = __shfl_up(v, o);
            if ((tid & 63) >= o) v += t;
        }
        if ((tid & 63) == 63) wsum[tid >> 6] = v;
        __syncthreads();
        u32 woff = 0;
        #pragma unroll
        for (int w = 0; w < 3; ++w) woff += (w < (tid >> 6)) ? wsum[w] : 0;
        u32 run = v + woff - tot;                // exclusive base for sub 4*tid
        uint4 mv;
        lstart[4 * tid + 0] = run; mv.x = (run << 16) | c0; run += c0;
        lstart[4 * tid + 1] = run; mv.y = (run << 16) | c1; run += c1;
        lstart[4 * tid + 2] = run; mv.z = (run << 16) | c2; run += c2;
        lstart[4 * tid + 3] = run; mv.w = (run << 16) | c3;
        ((uint4*)metaArr)[blk * 256 + tid] = mv;     // coalesced 16 B store
    }
    if (tid < NC) ntPart[blk * 160 + tid] = (u16)nth[tid];
    __syncthreads();

    // ---- phase C: rank-based scatter into staging (no atomics) ----
    #pragma unroll
    for (int k = 0; k < 16; ++k) {
        int flat = tid * 16 + k;
        u32 v = keybuf[flat];
        staging[lstart[v >> 16] + (u32)rankbuf[flat]] = (u16)(v & 0xFFFFu);
    }
    __syncthreads();

    // ---- phase D: contiguous vectorized flush (8 KB as 512 uint4) ----
    {
        const uint4* s4 = (const uint4*)staging;
        uint4* d4 = (uint4*)(recSeg + (size_t)blk * SEGPIX);
        d4[tid]       = s4[tid];
        d4[tid + 256] = s4[tid + 256];
    }
}

// ---------------------------------------------------------------------------
// Kernel 2 (helper): blocks 0..255 transpose meta[seg][sub] -> metaT[sub][seg]
// (tiled 64x64 via LDS, both sides coalesced, conflict-free +1 pad);
// blocks 256..271 reduce nt partials -> gNT. Still one graph node.
// ---------------------------------------------------------------------------
__global__ __launch_bounds__(256) void helper_kernel(const u16* __restrict__ ntPart,
                                                     u32* __restrict__ gNT,
                                                     const u32* __restrict__ metaArr,
                                                     u32* __restrict__ metaT) {
    int tid = threadIdx.x;
    if (blockIdx.x < 256) {
        __shared__ u32 tile[64][65];
        int tr = blockIdx.x >> 4, tc = blockIdx.x & 15;   // tile row (seg), col (sub)
        for (int i = tid; i < 64 * 64; i += 256) {
            int r = i >> 6, c = i & 63;
            tile[r][c] = metaArr[(size_t)(tr * 64 + r) * NSUB + (tc * 64 + c)];
        }
        __syncthreads();
        for (int i = tid; i < 64 * 64; i += 256) {
            int r = i >> 6, c = i & 63;
            metaT[(size_t)(tc * 64 + r) * SEGS + (tr * 64 + c)] = tile[c][r];
        }
    } else {
        int img = blockIdx.x - 256;
        if (tid < NC) {
            u32 s = 0;
            #pragma unroll 8
            for (int b2 = 0; b2 < SEGS / B_; ++b2)
                s += ntPart[(img * (SEGS / B_) + b2) * 160 + tid];
            gNT[img * NC + tid] = s;
        }
    }
}

// ---------------------------------------------------------------------------
// Kernel 3: one block per sub-bucket (4 pred rows). metaT row is read
// CONTIGUOUSLY (64 coalesced lines vs 1024 scattered) -- scan line count
// per block drops ~2x. Record runs unchanged (~1 line each).
// ---------------------------------------------------------------------------
__global__ __launch_bounds__(256, 7) void iou_kernel(const u16* __restrict__ recSeg,
                                                     const u32* __restrict__ metaT,
                                                     const u32* __restrict__ gNT,
                                                     const float* __restrict__ targets,
                                                     float* __restrict__ out) {
    __shared__ u32 hist[QT / 2];              // 4800 words = 19.2 KB
    __shared__ float npred_s[4];
    __shared__ float iou_pc[4][NC];           // 2.4 KB
    __shared__ float4 wred[4];                // per-wave partial denominators

    int tid = threadIdx.x;
    int sub = blockIdx.x;                     // 0..1023
    u32 lo = (u32)((sub & 3) * QT);

    // vectorized hist zero
    {
        uint4 z4 = make_uint4(0u, 0u, 0u, 0u);
        uint4* h4 = (uint4*)hist;
        for (int j = tid; j < QT / 8; j += 256) h4[j] = z4;
    }
    __syncthreads();

    // scan: 4 segments per thread; meta reads coalesced from metaT row
    const u32* mrow = metaT + (size_t)sub * SEGS;
    for (int s = tid; s < SEGS; s += 256) {
        u32 m  = mrow[s];                     // lane-contiguous -> coalesced
        u32 ls = m >> 16;
        u32 n  = m & 0xFFFFu;
        if (!n) continue;
        u32 je = ls + n;
        const u16* segp = recSeg + (size_t)s * SEGPIX;
        for (u32 j = ls & ~7u; j < je; j += 8) {
            uint4 v = *(const uint4*)(segp + j);
            u32 words[4] = {v.x, v.y, v.z, v.w};
            #pragma unroll
            for (int w = 0; w < 4; ++w) {
                #pragma unroll
                for (int h = 0; h < 2; ++h) {
                    u32 idx = j + (u32)(w * 2 + h);
                    if (idx >= ls && idx < je) {
                        u32 lk = ((words[w] >> (h * 16)) & 0xFFFFu) - lo;
                        if (lk < (u32)QT)
                            atomicAdd(&hist[lk >> 1], (lk & 1u) ? 65536u : 1u);
                    }
                }
            }
        }
    }
    __syncthreads();

    // n_pred row sums: 4 waves, one pred row each (1200 words)
    {
        int pl = tid >> 6, lane = tid & 63;
        u32 s = 0;
        for (int w = lane; w < T_ / 2; w += 64) {
            u32 v = hist[pl * (T_ / 2) + w];
            s += (v & 0xFFFFu) + (v >> 16);
        }
        #pragma unroll
        for (int o = 32; o > 0; o >>= 1) s += __shfl_xor(s, o);
        if (lane == 0) npred_s[pl] = (float)s;
    }
    __syncthreads();

    // iou_pc[pl][c] = sum_b O/(n_pred + n_tgt - O); gNT reads are L1-hot
    for (int idx = tid; idx < 4 * NC; idx += 256) {
        int pl = idx / NC, cls = idx - pl * NC;
        float np = npred_s[pl];
        float acc = 0.f;
        #pragma unroll
        for (int b = 0; b < B_; ++b) {
            int lk = pl * T_ + b * NC + cls;
            u32 w = hist[lk >> 1];
            u32 v = (lk & 1) ? (w >> 16) : (w & 0xFFFFu);
            if (v) {
                float fv = (float)v;
                acc += fv * __builtin_amdgcn_rcpf(np + (float)gNT[b * NC + cls] - fv);
            }
        }
        iou_pc[pl][cls] = acc;
    }
    __syncthreads();

    // matmul with targets (each element read once for all 4 rows)
    float o0 = 0.f, o1 = 0.f, o2 = 0.f, o3 = 0.f;
    if (tid < NC) {
        #pragma unroll 4
        for (int k = 0; k < NC; ++k) {
            float tv = targets[k * NC + tid];
            o0 += iou_pc[0][k] * tv;
            o1 += iou_pc[1][k] * tv;
            o2 += iou_pc[2][k] * tv;
            o3 += iou_pc[3][k] * tv;
        }
    }

    // denominator: wave shfl reduce -> 4 partials -> broadcast sum
    {
        float4 v = (tid < NC) ? make_float4(o0, o1, o2, o3)
                              : make_float4(0.f, 0.f, 0.f, 0.f);
        #pragma unroll
        for (int o = 32; o > 0; o >>= 1) {
            v.x += __shfl_xor(v.x, o);
            v.y += __shfl_xor(v.y, o);
            v.z += __shfl_xor(v.z, o);
            v.w += __shfl_xor(v.w, o);
        }
        if ((tid & 63) == 0) wred[tid >> 6] = v;
    }
    __syncthreads();
    float4 den;
    {
        float4 a = wred[0], b = wred[1], c = wred[2], d = wred[3];
        den = make_float4(a.x + b.x + c.x + d.x, a.y + b.y + c.y + d.y,
                          a.z + b.z + c.z + d.z, a.w + b.w + c.w + d.w);
    }

    if (tid < NC) {
        // preds covered: (sub>>2)*16 + (sub&3)*4 + pl
        size_t ob = (size_t)((sub >> 2) * 16 + (sub & 3) * 4) * NC + tid;
        out[ob + 0 * NC] = o0 * __builtin_amdgcn_rcpf(den.x);
        out[ob + 1 * NC] = o1 * __builtin_amdgcn_rcpf(den.y);
        out[ob + 2 * NC] = o2 * __builtin_amdgcn_rcpf(den.z);
        out[ob + 3 * NC] = o3 * __builtin_amdgcn_rcpf(den.w);
    }
}

// ---------------------------------------------------------------------------
extern "C" void kernel_launch(void* const* d_in, const int* in_sizes, int n_in,
                              void* d_out, int out_size, void* d_ws, size_t ws_size,
                              hipStream_t stream) {
    const int*   pred    = (const int*)d_in[0];
    const int*   tgt     = (const int*)d_in[1];
    const float* targets = (const float*)d_in[2];
    float*       out     = (float*)d_out;

    // ws layout (nothing needs pre-zeroing):
    u16* recSeg  = (u16*)d_ws;                               // 8.4 MB
    u32* metaArr = (u32*)(recSeg + (size_t)SEGS * SEGPIX);   // 4 MB
    u32* metaT   = metaArr + (size_t)SEGS * NSUB;            // 4 MB (transposed)
    u16* ntPart  = (u16*)(metaT + (size_t)NSUB * SEGS);      // 320 KB
    u32* gNT     = (u32*)(ntPart + SEGS * 160);              // 2400 u32

    partition_kernel<<<SEGS, 256, 0, stream>>>(pred, tgt, recSeg, metaArr, ntPart);
    helper_kernel<<<256 + B_, 256, 0, stream>>>(ntPart, gNT, metaArr, metaT);
    iou_kernel<<<NSUB, 256, 0, stream>>>(recSeg, metaT, gNT, targets, out);
}

// Round 19
// 59.870 us; speedup vs baseline: 1.0923x; 1.0923x over previous
//
#include <hip/hip_runtime.h>

// Problem constants (fixed by setup_inputs)
#define B_    16
#define N_    262144            // 2^18 pixels per image
#define NC    150               // classes
#define NP    4096              // pred segment ids
#define T_    (B_ * NC)         // 2400 distinct target ids
#define TOTAL (B_ * N_)         // 4,194,304 pixels

#define NSUB   1024             // sub-buckets (pred>>2), 4 pred rows each
#define SEGS   1024             // partition blocks
#define SEGPIX 4096             // pixels (records) per segment
#define QT     9600             // local keys per sub-bucket block (4*2400)

typedef unsigned int u32;
typedef unsigned short u16;

// ---------------------------------------------------------------------------
// Kernel 1: staged radix-split by pred>>2 (1024 bins), single input pass,
// rank-fused, contiguous flush. meta[(seg,sub)] = (lstart<<16)|cnt.
// ---------------------------------------------------------------------------
__global__ __launch_bounds__(256) void partition_kernel(const int* __restrict__ pred,
                                                        const int* __restrict__ tgt,
                                                        u16* __restrict__ recSeg,
                                                        u32* __restrict__ metaArr,
                                                        u16* __restrict__ ntPart) {
    __shared__ u32 keybuf[SEGPIX];   // 16 KB: (sub<<16)|lk
    __shared__ u16 rankbuf[SEGPIX];  // 8 KB: within-(block,sub) rank
    __shared__ u16 staging[SEGPIX];  // 8 KB: sub-bucket-sorted u16 records
    __shared__ u32 cnt32[NSUB / 2];  // 2 KB: two u16 counters per word
    __shared__ u32 lstart[NSUB];     // 4 KB
    __shared__ u32 nth[NC];          // 600 B
    __shared__ u32 wsum[4];

    int tid = threadIdx.x;
    int blk = blockIdx.x;
    cnt32[tid] = 0;
    cnt32[tid + 256] = 0;
    if (tid < NC) nth[tid] = 0;
    __syncthreads();

    int base = blk * SEGPIX;
    int b_img = base >> 18;                  // constant per block
    const int4* pred4 = (const int4*)pred;
    const int4* tgt4  = (const int4*)tgt;

    // ---- phase A: read once; key + rank into LDS; packed counts ----
    #pragma unroll
    for (int k = 0; k < 4; ++k) {
        int vi = (base >> 2) + k * 256 + tid;
        int4 pv = pred4[vi];
        int4 tv = tgt4[vi];
        int pe[4] = {pv.x, pv.y, pv.z, pv.w};
        int te[4] = {tv.x, tv.y, tv.z, tv.w};
        #pragma unroll
        for (int e = 0; e < 4; ++e) {
            int p = pe[e];
            u32 sub = (u32)(p >> 2);
            u32 lk  = (u32)((p & 15) * T_ + b_img * NC + te[e]);
            int flat = (k * 256 + tid) * 4 + e;
            u32 shift = (sub & 1u) * 16u;
            u32 old = atomicAdd(&cnt32[sub >> 1], 1u << shift);
            keybuf[flat]  = (sub << 16) | lk;
            rankbuf[flat] = (u16)((old >> shift) & 0xFFFFu);
            atomicAdd(&nth[te[e]], 1u);
        }
    }
    __syncthreads();

    // ---- phase B: two-level exclusive scan over 1024 counts ----
    {
        u32 w0 = cnt32[2 * tid], w1 = cnt32[2 * tid + 1];
        u32 c0 = w0 & 0xFFFFu, c1 = w0 >> 16, c2 = w1 & 0xFFFFu, c3 = w1 >> 16;
        u32 tot = c0 + c1 + c2 + c3;
        u32 v = tot;
        #pragma unroll
        for (int o = 1; o < 64; o <<= 1) {
            u32 t = __shfl_up(v, o);
            if ((tid & 63) >= o) v += t;
        }
        if ((tid & 63) == 63) wsum[tid >> 6] = v;
        __syncthreads();
        u32 woff = 0;
        #pragma unroll
        for (int w = 0; w < 3; ++w) woff += (w < (tid >> 6)) ? wsum[w] : 0;
        u32 run = v + woff - tot;                // exclusive base for sub 4*tid
        uint4 mv;
        lstart[4 * tid + 0] = run; mv.x = (run << 16) | c0; run += c0;
        lstart[4 * tid + 1] = run; mv.y = (run << 16) | c1; run += c1;
        lstart[4 * tid + 2] = run; mv.z = (run << 16) | c2; run += c2;
        lstart[4 * tid + 3] = run; mv.w = (run << 16) | c3;
        ((uint4*)metaArr)[blk * 256 + tid] = mv;     // coalesced 16 B store
    }
    if (tid < NC) ntPart[blk * 160 + tid] = (u16)nth[tid];
    __syncthreads();

    // ---- phase C: rank-based scatter into staging (no atomics) ----
    #pragma unroll
    for (int k = 0; k < 16; ++k) {
        int flat = tid * 16 + k;
        u32 v = keybuf[flat];
        staging[lstart[v >> 16] + (u32)rankbuf[flat]] = (u16)(v & 0xFFFFu);
    }
    __syncthreads();

    // ---- phase D: contiguous vectorized flush (8 KB as 512 uint4) ----
    {
        const uint4* s4 = (const uint4*)staging;
        uint4* d4 = (uint4*)(recSeg + (size_t)blk * SEGPIX);
        d4[tid]       = s4[tid];
        d4[tid + 256] = s4[tid + 256];
    }
}

// ---------------------------------------------------------------------------
// Kernel 2: reduce nt partials -> gNT. Single-writer, no atomics, no init.
// ---------------------------------------------------------------------------
__global__ __launch_bounds__(256) void ntreduce(const u16* __restrict__ ntPart,
                                                u32* __restrict__ gNT) {
    int img = blockIdx.x;
    int c = threadIdx.x;
    if (c < NC) {
        u32 s = 0;
        #pragma unroll 8
        for (int b2 = 0; b2 < SEGS / B_; ++b2)      // 64 partition blocks per image
            s += ntPart[(img * (SEGS / B_) + b2) * 160 + c];
        gNT[img * NC + c] = s;
    }
}

// ---------------------------------------------------------------------------
// Kernel 3: one block per sub-bucket (4 pred rows). Batched-ILP scan:
// all 4 meta loads issued together, then all 4 first-run-line loads,
// collapsing 4 serial latency chains into ~1.
// ---------------------------------------------------------------------------
__global__ __launch_bounds__(256, 7) void iou_kernel(const u16* __restrict__ recSeg,
                                                     const u32* __restrict__ metaArr,
                                                     const u32* __restrict__ gNT,
                                                     const float* __restrict__ targets,
                                                     float* __restrict__ out) {
    __shared__ u32 hist[QT / 2];              // 4800 words = 19.2 KB
    __shared__ float npred_s[4];
    __shared__ float iou_pc[4][NC];           // 2.4 KB
    __shared__ float4 wred[4];                // per-wave partial denominators

    int tid = threadIdx.x;
    int sub = blockIdx.x;                     // 0..1023
    u32 lo = (u32)((sub & 3) * QT);

    // vectorized hist zero
    {
        uint4 z4 = make_uint4(0u, 0u, 0u, 0u);
        uint4* h4 = (uint4*)hist;
        for (int j = tid; j < QT / 8; j += 256) h4[j] = z4;
    }
    __syncthreads();

    // ---- batched scan: 4 segments per thread, loads overlapped ----
    {
        u32 mm[4];
        #pragma unroll
        for (int k = 0; k < 4; ++k)
            mm[k] = metaArr[(size_t)(tid + 256 * k) * NSUB + sub];

        u32 ls[4], je[4];
        uint4 first[4];
        #pragma unroll
        for (int k = 0; k < 4; ++k) {
            ls[k] = mm[k] >> 16;
            u32 n = mm[k] & 0xFFFFu;
            je[k] = ls[k] + n;
            const u16* segp = recSeg + (size_t)(tid + 256 * k) * SEGPIX;
            if (n) first[k] = *(const uint4*)(segp + (ls[k] & ~7u));
        }

        #pragma unroll
        for (int k = 0; k < 4; ++k) {
            if (je[k] == ls[k]) continue;
            const u16* segp = recSeg + (size_t)(tid + 256 * k) * SEGPIX;
            u32 j = ls[k] & ~7u;
            uint4 v = first[k];
            for (;;) {
                u32 words[4] = {v.x, v.y, v.z, v.w};
                #pragma unroll
                for (int w = 0; w < 4; ++w) {
                    #pragma unroll
                    for (int h = 0; h < 2; ++h) {
                        u32 idx = j + (u32)(w * 2 + h);
                        if (idx >= ls[k] && idx < je[k]) {
                            u32 lk = ((words[w] >> (h * 16)) & 0xFFFFu) - lo;
                            if (lk < (u32)QT)
                                atomicAdd(&hist[lk >> 1], (lk & 1u) ? 65536u : 1u);
                        }
                    }
                }
                j += 8;
                if (j >= je[k]) break;
                v = *(const uint4*)(segp + j);
            }
        }
    }
    __syncthreads();

    // n_pred row sums: 4 waves, one pred row each (1200 words)
    {
        int pl = tid >> 6, lane = tid & 63;
        u32 s = 0;
        for (int w = lane; w < T_ / 2; w += 64) {
            u32 v = hist[pl * (T_ / 2) + w];
            s += (v & 0xFFFFu) + (v >> 16);
        }
        #pragma unroll
        for (int o = 32; o > 0; o >>= 1) s += __shfl_xor(s, o);
        if (lane == 0) npred_s[pl] = (float)s;
    }
    __syncthreads();

    // iou_pc[pl][c] = sum_b O/(n_pred + n_tgt - O); gNT reads are L1-hot
    for (int idx = tid; idx < 4 * NC; idx += 256) {
        int pl = idx / NC, cls = idx - pl * NC;
        float np = npred_s[pl];
        float acc = 0.f;
        #pragma unroll
        for (int b = 0; b < B_; ++b) {
            int lk = pl * T_ + b * NC + cls;
            u32 w = hist[lk >> 1];
            u32 v = (lk & 1) ? (w >> 16) : (w & 0xFFFFu);
            if (v) {
                float fv = (float)v;
                acc += fv * __builtin_amdgcn_rcpf(np + (float)gNT[b * NC + cls] - fv);
            }
        }
        iou_pc[pl][cls] = acc;
    }
    __syncthreads();

    // matmul with targets (each element read once for all 4 rows)
    float o0 = 0.f, o1 = 0.f, o2 = 0.f, o3 = 0.f;
    if (tid < NC) {
        for (int k = 0; k < NC; ++k) {
            float tv = targets[k * NC + tid];
            o0 += iou_pc[0][k] * tv;
            o1 += iou_pc[1][k] * tv;
            o2 += iou_pc[2][k] * tv;
            o3 += iou_pc[3][k] * tv;
        }
    }

    // denominator: wave shfl reduce -> 4 partials -> broadcast sum
    {
        float4 v = (tid < NC) ? make_float4(o0, o1, o2, o3)
                              : make_float4(0.f, 0.f, 0.f, 0.f);
        #pragma unroll
        for (int o = 32; o > 0; o >>= 1) {
            v.x += __shfl_xor(v.x, o);
            v.y += __shfl_xor(v.y, o);
            v.z += __shfl_xor(v.z, o);
            v.w += __shfl_xor(v.w, o);
        }
        if ((tid & 63) == 0) wred[tid >> 6] = v;
    }
    __syncthreads();
    float4 den;
    {
        float4 a = wred[0], b = wred[1], c = wred[2], d = wred[3];
        den = make_float4(a.x + b.x + c.x + d.x, a.y + b.y + c.y + d.y,
                          a.z + b.z + c.z + d.z, a.w + b.w + c.w + d.w);
    }

    if (tid < NC) {
        // preds covered: (sub>>2)*16 + (sub&3)*4 + pl
        size_t ob = (size_t)((sub >> 2) * 16 + (sub & 3) * 4) * NC + tid;
        out[ob + 0 * NC] = o0 * __builtin_amdgcn_rcpf(den.x);
        out[ob + 1 * NC] = o1 * __builtin_amdgcn_rcpf(den.y);
        out[ob + 2 * NC] = o2 * __builtin_amdgcn_rcpf(den.z);
        out[ob + 3 * NC] = o3 * __builtin_amdgcn_rcpf(den.w);
    }
}

// ---------------------------------------------------------------------------
extern "C" void kernel_launch(void* const* d_in, const int* in_sizes, int n_in,
                              void* d_out, int out_size, void* d_ws, size_t ws_size,
                              hipStream_t stream) {
    const int*   pred    = (const int*)d_in[0];
    const int*   tgt     = (const int*)d_in[1];
    const float* targets = (const float*)d_in[2];
    float*       out     = (float*)d_out;

    // ws layout (nothing needs pre-zeroing):
    u16* recSeg  = (u16*)d_ws;                               // 8.4 MB
    u32* metaArr = (u32*)(recSeg + (size_t)SEGS * SEGPIX);   // 4 MB
    u16* ntPart  = (u16*)(metaArr + (size_t)SEGS * NSUB);    // 320 KB
    u32* gNT     = (u32*)(ntPart + SEGS * 160);              // 2400 u32

    partition_kernel<<<SEGS, 256, 0, stream>>>(pred, tgt, recSeg, metaArr, ntPart);
    ntreduce<<<B_, 256, 0, stream>>>(ntPart, gNT);
    iou_kernel<<<NSUB, 256, 0, stream>>>(recSeg, metaArr, gNT, targets, out);
}

// Round 20
// 51.990 us; speedup vs baseline: 1.2578x; 1.1516x over previous
//
#include <hip/hip_runtime.h>

// Problem constants (fixed by setup_inputs)
#define B_    16
#define N_    262144            // 2^18 pixels per image
#define NC    150               // classes
#define NP    4096              // pred segment ids
#define T_    (B_ * NC)         // 2400 distinct target ids
#define TOTAL (B_ * N_)         // 4,194,304 pixels

#define NSUB   1024             // sub-buckets (pred>>2), 4 pred rows each
#define SEGS   1024             // partition blocks
#define SEGPIX 4096             // pixels (records) per segment
#define QT     9600             // local keys per sub-bucket block (4*2400)

typedef unsigned int u32;
typedef unsigned short u16;

// ---------------------------------------------------------------------------
// Kernel 1: staged radix-split by pred>>2 (1024 bins), single input pass,
// rank-fused, contiguous flush. meta[(seg,sub)] = (lstart<<16)|cnt.
// ---------------------------------------------------------------------------
__global__ __launch_bounds__(256, 4) void partition_kernel(const int* __restrict__ pred,
                                                           const int* __restrict__ tgt,
                                                           u16* __restrict__ recSeg,
                                                           u32* __restrict__ metaArr,
                                                           u16* __restrict__ ntPart) {
    __shared__ u32 keybuf[SEGPIX];   // 16 KB: (sub<<16)|lk
    __shared__ u16 rankbuf[SEGPIX];  // 8 KB: within-(block,sub) rank
    __shared__ u16 staging[SEGPIX];  // 8 KB: sub-bucket-sorted u16 records
    __shared__ u32 cnt32[NSUB / 2];  // 2 KB: two u16 counters per word
    __shared__ u32 lstart[NSUB];     // 4 KB
    __shared__ u32 nth[NC];          // 600 B
    __shared__ u32 wsum[4];

    int tid = threadIdx.x;
    int blk = blockIdx.x;
    cnt32[tid] = 0;
    cnt32[tid + 256] = 0;
    if (tid < NC) nth[tid] = 0;
    __syncthreads();

    int base = blk * SEGPIX;
    int b_img = base >> 18;                  // constant per block
    const int4* pred4 = (const int4*)pred;
    const int4* tgt4  = (const int4*)tgt;

    // ---- phase A: read once; key + rank into LDS; packed counts ----
    #pragma unroll
    for (int k = 0; k < 4; ++k) {
        int vi = (base >> 2) + k * 256 + tid;
        int4 pv = pred4[vi];
        int4 tv = tgt4[vi];
        int pe[4] = {pv.x, pv.y, pv.z, pv.w};
        int te[4] = {tv.x, tv.y, tv.z, tv.w};
        #pragma unroll
        for (int e = 0; e < 4; ++e) {
            int p = pe[e];
            u32 sub = (u32)(p >> 2);
            u32 lk  = (u32)((p & 15) * T_ + b_img * NC + te[e]);
            int flat = (k * 256 + tid) * 4 + e;
            u32 shift = (sub & 1u) * 16u;
            u32 old = atomicAdd(&cnt32[sub >> 1], 1u << shift);
            keybuf[flat]  = (sub << 16) | lk;
            rankbuf[flat] = (u16)((old >> shift) & 0xFFFFu);
            atomicAdd(&nth[te[e]], 1u);
        }
    }
    __syncthreads();

    // ---- phase B: two-level exclusive scan over 1024 counts ----
    {
        u32 w0 = cnt32[2 * tid], w1 = cnt32[2 * tid + 1];
        u32 c0 = w0 & 0xFFFFu, c1 = w0 >> 16, c2 = w1 & 0xFFFFu, c3 = w1 >> 16;
        u32 tot = c0 + c1 + c2 + c3;
        u32 v = tot;
        #pragma unroll
        for (int o = 1; o < 64; o <<= 1) {
            u32 t = __shfl_up(v, o);
            if ((tid & 63) >= o) v += t;
        }
        if ((tid & 63) == 63) wsum[tid >> 6] = v;
        __syncthreads();
        u32 woff = 0;
        #pragma unroll
        for (int w = 0; w < 3; ++w) woff += (w < (tid >> 6)) ? wsum[w] : 0;
        u32 run = v + woff - tot;                // exclusive base for sub 4*tid
        uint4 mv;
        lstart[4 * tid + 0] = run; mv.x = (run << 16) | c0; run += c0;
        lstart[4 * tid + 1] = run; mv.y = (run << 16) | c1; run += c1;
        lstart[4 * tid + 2] = run; mv.z = (run << 16) | c2; run += c2;
        lstart[4 * tid + 3] = run; mv.w = (run << 16) | c3;
        ((uint4*)metaArr)[blk * 256 + tid] = mv;     // coalesced 16 B store
    }
    if (tid < NC) ntPart[blk * 160 + tid] = (u16)nth[tid];
    __syncthreads();

    // ---- phase C: rank-based scatter into staging (no atomics) ----
    #pragma unroll
    for (int k = 0; k < 16; ++k) {
        int flat = tid * 16 + k;
        u32 v = keybuf[flat];
        staging[lstart[v >> 16] + (u32)rankbuf[flat]] = (u16)(v & 0xFFFFu);
    }
    __syncthreads();

    // ---- phase D: contiguous vectorized flush (8 KB as 512 uint4) ----
    {
        const uint4* s4 = (const uint4*)staging;
        uint4* d4 = (uint4*)(recSeg + (size_t)blk * SEGPIX);
        d4[tid]       = s4[tid];
        d4[tid + 256] = s4[tid + 256];
    }
}

// ---------------------------------------------------------------------------
// Kernel 2: reduce nt partials -> gNT. Single-writer, no atomics, no init.
// ---------------------------------------------------------------------------
__global__ __launch_bounds__(256) void ntreduce(const u16* __restrict__ ntPart,
                                                u32* __restrict__ gNT) {
    int img = blockIdx.x;
    int c = threadIdx.x;
    if (c < NC) {
        u32 s = 0;
        #pragma unroll 8
        for (int b2 = 0; b2 < SEGS / B_; ++b2)      // 64 partition blocks per image
            s += ntPart[(img * (SEGS / B_) + b2) * 160 + c];
        gNT[img * NC + c] = s;
    }
}

// ---------------------------------------------------------------------------
// Kernel 3: one block per sub-bucket (4 pred rows). Reads only its own
// per-segment runs via meta. XCD co-location: the 4 subs of one parent
// bucket map to blockIdx ≡ same (mod 8) -> shared boundary lines L2-hit.
// ---------------------------------------------------------------------------
__global__ __launch_bounds__(256, 7) void iou_kernel(const u16* __restrict__ recSeg,
                                                     const u32* __restrict__ metaArr,
                                                     const u32* __restrict__ gNT,
                                                     const float* __restrict__ targets,
                                                     float* __restrict__ out) {
    __shared__ u32 hist[QT / 2];              // 4800 words = 19.2 KB
    __shared__ float npred_s[4];
    __shared__ float iou_pc[4][NC];           // 2.4 KB
    __shared__ float4 wred[4];                // per-wave partial denominators

    int tid = threadIdx.x;
    int sub = 4 * (blockIdx.x & 255) + (blockIdx.x >> 8);   // co-locate parent's 4 subs
    u32 lo = (u32)((sub & 3) * QT);

    // vectorized hist zero
    {
        uint4 z4 = make_uint4(0u, 0u, 0u, 0u);
        uint4* h4 = (uint4*)hist;
        for (int j = tid; j < QT / 8; j += 256) h4[j] = z4;
    }
    __syncthreads();

    // scan: 4 segments per thread, each a ~4-record contiguous run
    for (int s = tid; s < SEGS; s += 256) {
        u32 m  = metaArr[s * NSUB + sub];
        u32 ls = m >> 16;
        u32 n  = m & 0xFFFFu;
        if (!n) continue;
        u32 je = ls + n;
        const u16* segp = recSeg + (size_t)s * SEGPIX;
        for (u32 j = ls & ~7u; j < je; j += 8) {
            uint4 v = *(const uint4*)(segp + j);
            u32 words[4] = {v.x, v.y, v.z, v.w};
            #pragma unroll
            for (int w = 0; w < 4; ++w) {
                #pragma unroll
                for (int h = 0; h < 2; ++h) {
                    u32 idx = j + (u32)(w * 2 + h);
                    if (idx >= ls && idx < je) {
                        u32 lk = ((words[w] >> (h * 16)) & 0xFFFFu) - lo;
                        if (lk < (u32)QT)
                            atomicAdd(&hist[lk >> 1], (lk & 1u) ? 65536u : 1u);
                    }
                }
            }
        }
    }
    __syncthreads();

    // n_pred row sums: 4 waves, one pred row each (1200 words)
    {
        int pl = tid >> 6, lane = tid & 63;
        u32 s = 0;
        for (int w = lane; w < T_ / 2; w += 64) {
            u32 v = hist[pl * (T_ / 2) + w];
            s += (v & 0xFFFFu) + (v >> 16);
        }
        #pragma unroll
        for (int o = 32; o > 0; o >>= 1) s += __shfl_xor(s, o);
        if (lane == 0) npred_s[pl] = (float)s;
    }
    __syncthreads();

    // iou_pc[pl][c] = sum_b O/(n_pred + n_tgt - O); gNT reads are L1-hot
    for (int idx = tid; idx < 4 * NC; idx += 256) {
        int pl = idx / NC, cls = idx - pl * NC;
        float np = npred_s[pl];
        float acc = 0.f;
        #pragma unroll
        for (int b = 0; b < B_; ++b) {
            int lk = pl * T_ + b * NC + cls;
            u32 w = hist[lk >> 1];
            u32 v = (lk & 1) ? (w >> 16) : (w & 0xFFFFu);
            if (v) {
                float fv = (float)v;
                acc += fv * __builtin_amdgcn_rcpf(np + (float)gNT[b * NC + cls] - fv);
            }
        }
        iou_pc[pl][cls] = acc;
    }
    __syncthreads();

    // matmul with targets (each element read once for all 4 rows)
    float o0 = 0.f, o1 = 0.f, o2 = 0.f, o3 = 0.f;
    if (tid < NC) {
        for (int k = 0; k < NC; ++k) {
            float tv = targets[k * NC + tid];
            o0 += iou_pc[0][k] * tv;
            o1 += iou_pc[1][k] * tv;
            o2 += iou_pc[2][k] * tv;
            o3 += iou_pc[3][k] * tv;
        }
    }

    // denominator: wave shfl reduce -> 4 partials -> broadcast sum
    {
        float4 v = (tid < NC) ? make_float4(o0, o1, o2, o3)
                              : make_float4(0.f, 0.f, 0.f, 0.f);
        #pragma unroll
        for (int o = 32; o > 0; o >>= 1) {
            v.x += __shfl_xor(v.x, o);
            v.y += __shfl_xor(v.y, o);
            v.z += __shfl_xor(v.z, o);
            v.w += __shfl_xor(v.w, o);
        }
        if ((tid & 63) == 0) wred[tid >> 6] = v;
    }
    __syncthreads();
    float4 den;
    {
        float4 a = wred[0], b = wred[1], c = wred[2], d = wred[3];
        den = make_float4(a.x + b.x + c.x + d.x, a.y + b.y + c.y + d.y,
                          a.z + b.z + c.z + d.z, a.w + b.w + c.w + d.w);
    }

    if (tid < NC) {
        // preds covered: (sub>>2)*16 + (sub&3)*4 + pl
        size_t ob = (size_t)((sub >> 2) * 16 + (sub & 3) * 4) * NC + tid;
        out[ob + 0 * NC] = o0 * __builtin_amdgcn_rcpf(den.x);
        out[ob + 1 * NC] = o1 * __builtin_amdgcn_rcpf(den.y);
        out[ob + 2 * NC] = o2 * __builtin_amdgcn_rcpf(den.z);
        out[ob + 3 * NC] = o3 * __builtin_amdgcn_rcpf(den.w);
    }
}

// ---------------------------------------------------------------------------
extern "C" void kernel_launch(void* const* d_in, const int* in_sizes, int n_in,
                              void* d_out, int out_size, void* d_ws, size_t ws_size,
                              hipStream_t stream) {
    const int*   pred    = (const int*)d_in[0];
    const int*   tgt     = (const int*)d_in[1];
    const float* targets = (const float*)d_in[2];
    float*       out     = (float*)d_out;

    // ws layout (nothing needs pre-zeroing):
    u16* recSeg  = (u16*)d_ws;                               // 8.4 MB
    u32* metaArr = (u32*)(recSeg + (size_t)SEGS * SEGPIX);   // 4 MB
    u16* ntPart  = (u16*)(metaArr + (size_t)SEGS * NSUB);    // 320 KB
    u32* gNT     = (u32*)(ntPart + SEGS * 160);              // 2400 u32

    partition_kernel<<<SEGS, 256, 0, stream>>>(pred, tgt, recSeg, metaArr, ntPart);
    ntreduce<<<B_, 256, 0, stream>>>(ntPart, gNT);
    iou_kernel<<<NSUB, 256, 0, stream>>>(recSeg, metaArr, gNT, targets, out);
}